// Round 1
// baseline (194.304 us; speedup 1.0000x reference)
//
#include <hip/hip_runtime.h>

#define EPSV 1e-5f

__device__ __forceinline__ float sigmoidf_(float z) {
    return 1.0f / (1.0f + __expf(-z));
}

// One block per (b,g) group: 64 channels x 784 pixels = 50176 floats staged in
// registers. tid = cc*16 + ts; thread owns float4 indices ts+16k (k<12) of its
// channel row, lanes ts<4 take one extra (196 = 16*12 + 4).
__global__ __launch_bounds__(1024, 4) void fused_sgate_kernel(
    const float* __restrict__ x,
    const float* __restrict__ cweight,
    const float* __restrict__ cbias,
    const float* __restrict__ sweight,
    const float* __restrict__ sbias,
    float* __restrict__ out)
{
    constexpr int HW = 784;
    constexpr int CG = 64;
    constexpr int NELEM = CG * HW;    // 50176 floats per (b,g) group

    const int bg  = blockIdx.x;       // 0..B*8-1
    const int b   = bg >> 3;
    const int g   = bg & 7;
    const int tid = threadIdx.x;      // 0..1023
    const int cc  = tid >> 4;         // 0..63 channel within group
    const int ts  = tid & 15;         // 0..15 sub-thread within channel

    const float4* __restrict__ xch =
        (const float4*)(x + (size_t)bg * NELEM + (size_t)cc * HW);

    float4 v[13];
#pragma unroll
    for (int k = 0; k < 12; ++k) v[k] = xch[ts + 16 * k];
    const bool extra = (ts < 4);
    v[12] = make_float4(0.f, 0.f, 0.f, 0.f);
    if (extra) v[12] = xch[192 + ts];

    // thread-local sum / sumsq over staged elements
    float s = 0.f, ss = 0.f;
#pragma unroll
    for (int k = 0; k < 13; ++k) {
        s  += (v[k].x + v[k].y) + (v[k].z + v[k].w);
        ss += (v[k].x * v[k].x + v[k].y * v[k].y)
            + (v[k].z * v[k].z + v[k].w * v[k].w);
    }

    // 16-lane cluster reduction -> per-channel sum (one channel per cluster)
#pragma unroll
    for (int m = 8; m >= 1; m >>= 1) {
        s  += __shfl_xor(s,  m, 64);
        ss += __shfl_xor(ss, m, 64);
    }
    const float chan_sum = s;   // sum over this channel's 784 elements

    // continue to full-wave sums (4 channels per wave)
    s  += __shfl_xor(s, 16, 64);
    s  += __shfl_xor(s, 32, 64);
    ss += __shfl_xor(ss, 16, 64);
    ss += __shfl_xor(ss, 32, 64);

    __shared__ float lds_s[16];
    __shared__ float lds_ss[16];
    __shared__ float lds_stats[2];   // mu, rstd for the x1 half (cc>=32)

    const int w = tid >> 6;          // wave id 0..15; waves 8-15 hold cc>=32
    if ((tid & 63) == 0) { lds_s[w] = s; lds_ss[w] = ss; }
    __syncthreads();
    if (tid == 0) {
        float S = 0.f, SS = 0.f;
#pragma unroll
        for (int i = 8; i < 16; ++i) { S += lds_s[i]; SS += lds_ss[i]; }
        constexpr float inv_n = 1.0f / (32.0f * 784.0f);
        const float mu   = S * inv_n;
        const float var  = SS * inv_n - mu * mu;
        const float rstd = rsqrtf(fmaxf(var, 0.f) + EPSV);
        lds_stats[0] = mu;
        lds_stats[1] = rstd;
    }
    __syncthreads();

    // Output channel shuffle: concat channel c = g*64+cc -> out channel
    // c' = 2*(c%256) + c/256.
    const int c_concat = g * CG + cc;
    const int cp = (c_concat < 256) ? (2 * c_concat)
                                    : (2 * (c_concat - 256) + 1);
    float4* __restrict__ och =
        (float4*)(out + (size_t)b * (512 * HW) + (size_t)cp * HW);

    if (cc < 32) {
        // channel-gate branch: a0 = sigmoid(cw*mean + cb), y = x*a0
        const float mval = chan_sum * (1.0f / 784.0f);
        const float a0 = sigmoidf_(cweight[cc] * mval + cbias[cc]);
#pragma unroll
        for (int k = 0; k < 12; ++k) {
            float4 r;
            r.x = v[k].x * a0; r.y = v[k].y * a0;
            r.z = v[k].z * a0; r.w = v[k].w * a0;
            och[ts + 16 * k] = r;
        }
        if (extra) {
            float4 r;
            r.x = v[12].x * a0; r.y = v[12].y * a0;
            r.z = v[12].z * a0; r.w = v[12].w * a0;
            och[192 + ts] = r;
        }
    } else {
        // spatial-gate branch: y = x * sigmoid(sw*norm + sb)
        const float mu   = lds_stats[0];
        const float rstd = lds_stats[1];
        const float wgt  = sweight[cc - 32];
        const float bs   = sbias[cc - 32];
#pragma unroll
        for (int k = 0; k < 12; ++k) {
            float4 r;
            r.x = v[k].x * sigmoidf_(wgt * ((v[k].x - mu) * rstd) + bs);
            r.y = v[k].y * sigmoidf_(wgt * ((v[k].y - mu) * rstd) + bs);
            r.z = v[k].z * sigmoidf_(wgt * ((v[k].z - mu) * rstd) + bs);
            r.w = v[k].w * sigmoidf_(wgt * ((v[k].w - mu) * rstd) + bs);
            och[ts + 16 * k] = r;
        }
        if (extra) {
            float4 r;
            r.x = v[12].x * sigmoidf_(wgt * ((v[12].x - mu) * rstd) + bs);
            r.y = v[12].y * sigmoidf_(wgt * ((v[12].y - mu) * rstd) + bs);
            r.z = v[12].z * sigmoidf_(wgt * ((v[12].z - mu) * rstd) + bs);
            r.w = v[12].w * sigmoidf_(wgt * ((v[12].w - mu) * rstd) + bs);
            och[192 + ts] = r;
        }
    }
}

extern "C" void kernel_launch(void* const* d_in, const int* in_sizes, int n_in,
                              void* d_out, int out_size, void* d_ws, size_t ws_size,
                              hipStream_t stream) {
    const float* x  = (const float*)d_in[0];
    const float* cw = (const float*)d_in[1];
    const float* cb = (const float*)d_in[2];
    const float* sw = (const float*)d_in[3];
    const float* sb = (const float*)d_in[4];
    float* out = (float*)d_out;

    // B*C*H*W = in_sizes[0]; C=512, H=W=28, G=8 fixed by the reference shapes.
    const int B = in_sizes[0] / (512 * 784);
    const int nblocks = B * 8;   // one block per (b,g) group

    fused_sgate_kernel<<<nblocks, 1024, 0, stream>>>(x, cw, cb, sw, sb, out);
}